// Round 8
// baseline (80.670 us; speedup 1.0000x reference)
//
#include <hip/hip_runtime.h>

// 8-qubit batched statevector sim, v8: v5 math, de-unrolled CRX (I-cache theory).
//   16 lanes per element (s = lane&15), 16 float2 regs per lane, 4 elems/wave.
//   1024 blocks x 256 threads.
// Phase A layout L1: amp idx = r*16 + s ; qubits 0..3 -> r bits 3..0, 4..7 -> s bits 3..0.
// Phase B (post 16x16 DPP transpose) L2: idx = s*16 + r ; qubits 0..3 -> s bits,
// 4..7 -> r bits. CRX groups run in TWO runtime loops of 4 iterations; after each
// group the 4-bit reg index is rotated left so the control is always reg bit 3
// (all register indices stay compile-time; gates within a group commute, so the
// fixed body order is valid). Coefficients fetched by v_readlane with uniform idx.
// Cross-lane via DPP: xor1=quad_perm[1,0,3,2], xor2=quad_perm[2,3,0,1],
// xor4=half_mirror o quad_perm[3,2,1,0], xor8=row_ror:8.

static __device__ __forceinline__ float rlane(float v, int src) {
    return __int_as_float(__builtin_amdgcn_readlane(__float_as_int(v), src));
}
template <int CTRL>
static __device__ __forceinline__ float dppf(float x) {
    return __int_as_float(__builtin_amdgcn_update_dpp(0, __float_as_int(x), CTRL, 0xF, 0xF, true));
}
static __device__ __forceinline__ float xor1f(float x) { return dppf<0xB1>(x); }
static __device__ __forceinline__ float xor2f(float x) { return dppf<0x4E>(x); }
static __device__ __forceinline__ float xor4f(float x) { return dppf<0x1B>(dppf<0x141>(x)); }
static __device__ __forceinline__ float xor8f(float x) { return dppf<0x128>(x); }
static __device__ __forceinline__ float xorMf(float x, int m) {  // m compile-time after unroll
    if (m == 1) return xor1f(x);
    if (m == 2) return xor2f(x);
    if (m == 4) return xor4f(x);
    return xor8f(x);
}
static __device__ __forceinline__ float2 cmul(float2 a, float2 b) {
    float2 t;
    t.x = a.x * b.x - a.y * b.y;
    t.y = a.x * b.y + a.y * b.x;
    return t;
}
// CRX half-rotation: c*t - i*s*u  ->  (c*t.x + s*u.y, c*t.y - s*u.x)
static __device__ __forceinline__ float2 rotA(float2 t, float2 u, float c, float s) {
    float2 d;
    d.x = c * t.x + s * u.y;
    d.y = c * t.y - s * u.x;
    return d;
}

__global__ __launch_bounds__(256, 4) void qsim_kernel(const float* __restrict__ X,
                                                      const float* __restrict__ W,
                                                      float* __restrict__ out,
                                                      int B) {
    const int lane = threadIdx.x & 63;
    const int g = lane >> 4;   // element slot in wave
    const int s = lane & 15;   // sublane within element
    const int b = (blockIdx.x * 4 + (threadIdx.x >> 6)) * 4 + g;
    const bool active = (b < B);
    const int bc = active ? b : (B - 1);   // clamp loads; keep all lanes alive for DPP

    // ---- CRX trig: lane gi (<56) holds cos/sin of 0.5*W[1+i, j] (wave-shared) ----
    float gcv = 1.0f, gsv = 0.0f;
    if (lane < 56) {
        const int i = lane / 7;
        const int jj = lane - 7 * i;
        const int j = jj + (jj >= i ? 1 : 0);
        const float h = 0.5f * W[(1 + i) * 72 + j];
        __sincosf(h, &gsv, &gcv);
    }

    // ---- per-qubit fused H->RZ->RY first column (sublane q computes qubit q) ----
    float u0r, u0i, u1r, u1i;
    {
        const int q = s & 7;
        float2 xq = ((const float2*)X)[bc * 8 + q];
        float cz, sz, cy, sy;
        __sincosf(0.5f * xq.x, &sz, &cz);
        __sincosf(0.5f * xq.y, &sy, &cy);
        u0r = (cy - sy) * cz;  u0i = -(cy + sy) * sz;
        u1r = (cy + sy) * cz;  u1i = (cy - sy) * sz;
    }

    // ---- product state in L1 ----
    // lane part: qubits 4..7 -> s bits 3..0
    float2 P; P.x = 1.0f; P.y = 0.0f;
#pragma unroll
    for (int q = 4; q < 8; ++q) {
        const int src = (g << 4) + q;
        const float a0r = __shfl(u0r, src, 64), a0i = __shfl(u0i, src, 64);
        const float a1r = __shfl(u1r, src, 64), a1i = __shfl(u1i, src, 64);
        const int bit = (s >> (7 - q)) & 1;
        float2 v; v.x = bit ? a1r : a0r; v.y = bit ? a1i : a0i;
        P = cmul(P, v);
    }
    // reg part: qubits 0..3 -> r bits 3..0
    float2 w0[4], w1[4];
#pragma unroll
    for (int k = 0; k < 4; ++k) {
        const int src = (g << 4) + k;
        w0[k].x = __shfl(u0r, src, 64);  w0[k].y = __shfl(u0i, src, 64);
        w1[k].x = __shfl(u1r, src, 64);  w1[k].y = __shfl(u1i, src, 64);
    }
    float2 a[16];
    {
        float2 t1[2];
        t1[0] = w0[0];
        t1[1] = w1[0];
        float2 t2[4];
#pragma unroll
        for (int h = 0; h < 2; ++h) {
            t2[h * 2 + 0] = cmul(t1[h], w0[1]);
            t2[h * 2 + 1] = cmul(t1[h], w1[1]);
        }
        float2 t3[8];
#pragma unroll
        for (int h = 0; h < 4; ++h) {
            t3[h * 2 + 0] = cmul(t2[h], w0[2]);
            t3[h * 2 + 1] = cmul(t2[h], w1[2]);
        }
#pragma unroll
        for (int h = 0; h < 8; ++h) {
            a[h * 2 + 0] = cmul(P, cmul(t3[h], w0[3]));
            a[h * 2 + 1] = cmul(P, cmul(t3[h], w1[3]));
        }
    }

    // ---- CRZ ring fused into one diagonal phase per amp (L1 bit mapping) ----
    {
        const float wv0 = W[0], wv1 = W[1], wv2 = W[2], wv3 = W[3];
        const float wv4 = W[4], wv5 = W[5], wv6 = W[6], wv7 = W[7];
        const int s3 = (s >> 3) & 1, s2 = (s >> 2) & 1, s1 = (s >> 1) & 1, s0 = s & 1;
        float phiS = 0.0f;
        phiS += s3 ? (s2 ? wv4 : -wv4) : 0.0f;
        phiS += s2 ? (s1 ? wv5 : -wv5) : 0.0f;
        phiS += s1 ? (s0 ? wv6 : -wv6) : 0.0f;
        const float termA = s3 ? wv3 : -wv3;   // pair (4,3): ctrl r0, sign by s3
        const float termB = s0 ? wv7 : 0.0f;   // pair (0,7): ctrl s0, sign by r3
#pragma unroll
        for (int r = 0; r < 16; ++r) {
            const int b3 = (r >> 3) & 1, b2 = (r >> 2) & 1, b1 = (r >> 1) & 1, b0 = r & 1;
            float phi = phiS + (b3 ? termB : -termB);
            if (b3) phi += b2 ? wv0 : -wv0;
            if (b2) phi += b1 ? wv1 : -wv1;
            if (b1) phi += b0 ? wv2 : -wv2;
            if (b0) phi += termA;
            float2 ph;
            __sincosf(0.5f * phi, &ph.y, &ph.x);
            a[r] = cmul(a[r], ph);
        }
    }

    // ---- CRX phase A: groups i=0..3 in L1, runtime loop, ctrl always reg bit 3 ----
#pragma unroll 1
    for (int it = 0; it < 4; ++it) {
        // reg-target slots at rotated positions tp=2,1,0 (commuting within group)
#pragma unroll
        for (int tp = 2; tp >= 0; --tp) {
            const int p = (tp - it) & 3;          // original reg bit
            const int j = 3 - p;                  // target qubit
            const int gi = it * 7 + (j < it ? j : j - 1);
            const float c  = rlane(gcv, gi);
            const float sn = rlane(gsv, gi);
            const int mt = 1 << tp;
#pragma unroll
            for (int r = 8; r < 16; ++r) {        // ctrl (rotated bit3) = 1
                if (r & mt) continue;
                const int rp = r | mt;
                const float2 t = a[r], u = a[rp];
                a[r]  = rotA(t, u, c, sn);
                a[rp] = rotA(u, t, c, sn);
            }
        }
        // lane-target slots j=4..7 (ms = 8,4,2,1), DPPs batched ahead of FMAs
#pragma unroll
        for (int j = 4; j < 8; ++j) {
            const int gi = it * 7 + (j - 1);
            const float c  = rlane(gcv, gi);
            const float sn = rlane(gsv, gi);
            const int ms = 1 << (7 - j);
            float pr[8], pi[8];
#pragma unroll
            for (int r = 8; r < 16; ++r) { pr[r - 8] = xorMf(a[r].x, ms); pi[r - 8] = xorMf(a[r].y, ms); }
#pragma unroll
            for (int r = 8; r < 16; ++r) {
                float2 pp; pp.x = pr[r - 8]; pp.y = pi[r - 8];
                a[r] = rotA(a[r], pp, c, sn);
            }
        }
        // rotate reg index left: new a[((r<<1)|(r>>3))&15] = a[r]  (cycle moves)
        { float2 t = a[8];  a[8]  = a[4];  a[4]  = a[2];  a[2]  = a[1];  a[1]  = t; }
        { float2 t = a[9];  a[9]  = a[12]; a[12] = a[6];  a[6]  = a[3];  a[3]  = t; }
        { float2 t = a[5];  a[5]  = a[10]; a[10] = t; }
        { float2 t = a[11]; a[11] = a[13]; a[13] = a[14]; a[14] = a[7];  a[7]  = t; }
    }

    // ---- 16x16 transpose L1 -> L2 via xor-swap stages (k = 1,2,4,8) ----
#pragma unroll
    for (int k = 1; k <= 8; k <<= 1) {
        const bool sk = (s & k) != 0;
#pragma unroll
        for (int r = 0; r < 16; ++r) {
            if (r & k) continue;
            const int rp = r | k;
            float2 tp2, tr2;
            tp2.x = xorMf(a[rp].x, k); tp2.y = xorMf(a[rp].y, k);
            tr2.x = xorMf(a[r].x,  k); tr2.y = xorMf(a[r].y,  k);
            a[r].x  = sk ? tp2.x : a[r].x;
            a[r].y  = sk ? tp2.y : a[r].y;
            a[rp].x = sk ? a[rp].x : tr2.x;
            a[rp].y = sk ? a[rp].y : tr2.y;
        }
    }

    // ---- CRX phase B: groups i=4..7 in L2, runtime loop, ctrl always reg bit 3 ----
#pragma unroll 1
    for (int it = 0; it < 4; ++it) {
        const int i = it + 4;
        // lane-target slots j=0..3 (ms = 8,4,2,1) — reference order
#pragma unroll
        for (int j = 0; j < 4; ++j) {
            const int gi = i * 7 + j;
            const float c  = rlane(gcv, gi);
            const float sn = rlane(gsv, gi);
            const int ms = 1 << (3 - j);
            float pr[8], pi[8];
#pragma unroll
            for (int r = 8; r < 16; ++r) { pr[r - 8] = xorMf(a[r].x, ms); pi[r - 8] = xorMf(a[r].y, ms); }
#pragma unroll
            for (int r = 8; r < 16; ++r) {
                float2 pp; pp.x = pr[r - 8]; pp.y = pi[r - 8];
                a[r] = rotA(a[r], pp, c, sn);
            }
        }
        // reg-target slots tp=2,1,0
#pragma unroll
        for (int tp = 2; tp >= 0; --tp) {
            const int p = (tp - it) & 3;          // original reg bit
            const int j = 7 - p;                  // target qubit
            const int gi = i * 7 + (j < i ? j : j - 1);
            const float c  = rlane(gcv, gi);
            const float sn = rlane(gsv, gi);
            const int mt = 1 << tp;
#pragma unroll
            for (int r = 8; r < 16; ++r) {
                if (r & mt) continue;
                const int rp = r | mt;
                const float2 t = a[r], u = a[rp];
                a[r]  = rotA(t, u, c, sn);
                a[rp] = rotA(u, t, c, sn);
            }
        }
        // rotate reg index left
        { float2 t = a[8];  a[8]  = a[4];  a[4]  = a[2];  a[2]  = a[1];  a[1]  = t; }
        { float2 t = a[9];  a[9]  = a[12]; a[12] = a[6];  a[6]  = a[3];  a[3]  = t; }
        { float2 t = a[5];  a[5]  = a[10]; a[10] = t; }
        { float2 t = a[11]; a[11] = a[13]; a[13] = a[14]; a[14] = a[7];  a[7]  = t; }
    }

    // ---- probabilities + all 8 <Z_q>  (L2: r bits 3..0 = qubits 4..7, s bits 3..0 = q0..q3) ----
    float p[16];
#pragma unroll
    for (int r = 0; r < 16; ++r) p[r] = a[r].x * a[r].x + a[r].y * a[r].y;
    float s8[8], E7 = 0.0f;
#pragma unroll
    for (int k = 0; k < 8; ++k) { s8[k] = p[2 * k] + p[2 * k + 1]; E7 += p[2 * k] - p[2 * k + 1]; }
    float s4[4], E6 = 0.0f;
#pragma unroll
    for (int k = 0; k < 4; ++k) { s4[k] = s8[2 * k] + s8[2 * k + 1]; E6 += s8[2 * k] - s8[2 * k + 1]; }
    float s2a[2], E5 = 0.0f;
#pragma unroll
    for (int k = 0; k < 2; ++k) { s2a[k] = s4[2 * k] + s4[2 * k + 1]; E5 += s4[2 * k] - s4[2 * k + 1]; }
    float A  = s2a[0] + s2a[1];
    float E4 = s2a[0] - s2a[1];
    float D0, D1, D2, D3;
    { const float t = xor1f(A); D0 = A - t; A += t;
      E4 += xor1f(E4); E5 += xor1f(E5); E6 += xor1f(E6); E7 += xor1f(E7); }
    { const float t = xor2f(A); D1 = A - t; A += t;
      D0 += xor2f(D0);
      E4 += xor2f(E4); E5 += xor2f(E5); E6 += xor2f(E6); E7 += xor2f(E7); }
    { const float t = xor4f(A); D2 = A - t; A += t;
      D0 += xor4f(D0); D1 += xor4f(D1);
      E4 += xor4f(E4); E5 += xor4f(E5); E6 += xor4f(E6); E7 += xor4f(E7); }
    { const float t = xor8f(A); D3 = A - t;
      D0 += xor8f(D0); D1 += xor8f(D1); D2 += xor8f(D2);
      E4 += xor8f(E4); E5 += xor8f(E5); E6 += xor8f(E6); E7 += xor8f(E7); }

    if (s == 0 && active) {
        const float sc = 1.0f / 256.0f;  // (1/sqrt2)^8 squared, folded out of u's
        float* o = out + b * 8;
        o[0] = D3 * sc;
        o[1] = D2 * sc;
        o[2] = D1 * sc;
        o[3] = D0 * sc;
        o[4] = E4 * sc;
        o[5] = E5 * sc;
        o[6] = E6 * sc;
        o[7] = E7 * sc;
    }
}

extern "C" void kernel_launch(void* const* d_in, const int* in_sizes, int n_in,
                              void* d_out, int out_size, void* d_ws, size_t ws_size,
                              hipStream_t stream) {
    const float* X = (const float*)d_in[0];
    const float* W = (const float*)d_in[1];
    float* out = (float*)d_out;
    const int B = in_sizes[0] / 16;       // 2*N floats per row
    const int blocks = (B + 15) / 16;     // 4 waves x 4 elements per 256-thread block
    qsim_kernel<<<blocks, 256, 0, stream>>>(X, W, out, B);
}